// Round 4
// baseline (200.779 us; speedup 1.0000x reference)
//
#include <hip/hip_runtime.h>
#include <hip/hip_bf16.h>

// MaskedContrastiveLoss: loss = 0.5*[mean_i(rowLSE_i - pos_i) + mean_j(colLSE_j - pos_j)]
// logits = (A @ B^T) * (1/0.07), A,B: [256, 65536] fp32, L2-normalized rows.
//
// Single-dispatch design (R1 calibration: 1-dispatch graph overhead ~5us vs
// ~110us spread across inter-kernel boundaries in 2-4 dispatch variants):
//   memset(16B counters) -> mega kernel:
//     phase G: split-K bf16 MFMA GEMM, body verbatim from the 172us baseline
//     signal:  one t==0 release fetch_add per block (512 total; R1 died from
//              ~260k per-THREAD threadfences, not from fusion itself)
//     last 64 finishing blocks: acquire-spin till all 512 done, then
//       rows (4/block, partials L3-resident after release writebacks),
//       counter barrier, cols (4/block), float-atomic tree -> out.

#define D_DIM 65536
#define B_DIM 256
#define LDK 72  // padded LDS row stride (elements) to break bank conflicts
#define NFIN 64

constexpr float TEMP = 1.0f / 0.07f;

typedef short short8 __attribute__((ext_vector_type(8)));
typedef float floatx4 __attribute__((ext_vector_type(4)));

__device__ inline unsigned short f2bf(float f) {
  unsigned u = __builtin_bit_cast(unsigned, f);
  unsigned rounding = 0x7fffu + ((u >> 16) & 1u);  // RNE (inputs are finite/normal)
  return (unsigned short)((u + rounding) >> 16);
}

__device__ inline void st_bf16x4(unsigned short* dst, float4 v) {
  uint2 u;
  u.x = (unsigned)f2bf(v.x) | ((unsigned)f2bf(v.y) << 16);
  u.y = (unsigned)f2bf(v.z) | ((unsigned)f2bf(v.w) << 16);
  *(uint2*)dst = u;
}

// grid = 4*C blocks; block = 256 threads (4 waves).
// blockIdx.x -> (mt in {0,128}, nt in {0,128}, K-chunk)
__global__ __launch_bounds__(256, 2) void mega(
    const float* __restrict__ A, const float* __restrict__ Bm,
    float* __restrict__ partials, float* __restrict__ logits,
    unsigned* __restrict__ ctr, float* __restrict__ out, int Kc, int C) {
  const int bid = blockIdx.x;
  const int mt = (bid & 1) * 128;
  const int nt = ((bid >> 1) & 1) * 128;
  const int chunk = bid >> 2;
  const size_t k0 = (size_t)chunk * (size_t)Kc;

  __shared__ unsigned short As[128][LDK];
  __shared__ unsigned short Bs[128][LDK];

  const int t = threadIdx.x;
  const int lane = t & 63;
  const int w = t >> 6;          // wave 0..3
  const int wm = (w & 1) * 64;   // wave sub-tile origin
  const int wn = (w >> 1) * 64;

  // global staging indexing: 16 threads cover one row's 64 floats (16 x float4)
  const int lr = t >> 4;          // base row 0..15 (+p*16)
  const int lc = (t & 15) * 4;    // col within BK=64

  const float* Abase = A + (size_t)(mt + lr) * D_DIM + k0 + lc;
  const float* Bbase = Bm + (size_t)(nt + lr) * D_DIM + k0 + lc;

  floatx4 acc[4][4];
#pragma unroll
  for (int mb = 0; mb < 4; ++mb)
#pragma unroll
    for (int nb = 0; nb < 4; ++nb) acc[mb][nb] = (floatx4)0.f;

  float4 ra[8], rb[8];
  const int nst = Kc >> 6;  // stages of BK=64

  // prefetch stage 0
#pragma unroll
  for (int p = 0; p < 8; ++p) {
    ra[p] = *(const float4*)(Abase + (size_t)p * 16 * D_DIM);
    rb[p] = *(const float4*)(Bbase + (size_t)p * 16 * D_DIM);
  }

  for (int s = 0; s < nst; ++s) {
    // convert + stage into LDS
#pragma unroll
    for (int p = 0; p < 8; ++p) {
      st_bf16x4(&As[lr + p * 16][lc], ra[p]);
      st_bf16x4(&Bs[lr + p * 16][lc], rb[p]);
    }
    __syncthreads();

    // issue next stage's global loads (overlap with MFMA below)
    if (s + 1 < nst) {
      const float* Ap = Abase + (size_t)(s + 1) * 64;
      const float* Bp = Bbase + (size_t)(s + 1) * 64;
#pragma unroll
      for (int p = 0; p < 8; ++p) {
        ra[p] = *(const float4*)(Ap + (size_t)p * 16 * D_DIM);
        rb[p] = *(const float4*)(Bp + (size_t)p * 16 * D_DIM);
      }
    }

    // MFMA over BK=64 (two K-steps of 32)
#pragma unroll
    for (int ks = 0; ks < 64; ks += 32) {
      short8 af[4], bf[4];
      const int ko = ks + (lane >> 4) * 8;
#pragma unroll
      for (int mb = 0; mb < 4; ++mb)
        af[mb] = *(const short8*)&As[wm + mb * 16 + (lane & 15)][ko];
#pragma unroll
      for (int nb = 0; nb < 4; ++nb)
        bf[nb] = *(const short8*)&Bs[wn + nb * 16 + (lane & 15)][ko];
#pragma unroll
      for (int mb = 0; mb < 4; ++mb)
#pragma unroll
        for (int nb = 0; nb < 4; ++nb)
          acc[mb][nb] = __builtin_amdgcn_mfma_f32_16x16x32_bf16(
              af[mb], bf[nb], acc[mb][nb], 0, 0, 0);
    }
    __syncthreads();
  }

  // epilogue: write partial tile. C/D layout: col=lane&15, row=(lane>>4)*4+reg
  float* outp = partials + (size_t)chunk * (B_DIM * B_DIM);
#pragma unroll
  for (int mb = 0; mb < 4; ++mb) {
#pragma unroll
    for (int nb = 0; nb < 4; ++nb) {
      const int gi0 = mt + wm + mb * 16 + ((lane >> 4) * 4);
      const int gj = nt + wn + nb * 16 + (lane & 15);
#pragma unroll
      for (int r = 0; r < 4; ++r)
        outp[(size_t)(gi0 + r) * B_DIM + gj] = acc[mb][nb][r];
    }
  }

  // ---- signal & elect finalizers (finish-order ranks) ----
  __syncthreads();  // compiler drains vmcnt(0) here: all partials stores done
  __shared__ unsigned srank;
  if (t == 0)
    srank = __hip_atomic_fetch_add(&ctr[0], 1u, __ATOMIC_ACQ_REL,
                                   __HIP_MEMORY_SCOPE_AGENT);
  __syncthreads();
  const unsigned nblk = gridDim.x;
  const unsigned nonfin = nblk - NFIN;
  const unsigned rank = srank;
  if (rank < nonfin) return;       // early finishers free their CU slots
  const int r = (int)(rank - nonfin);

  // wait until every block has published its partials (resident, so safe)
  if (t == 0) {
    while (__hip_atomic_load(&ctr[0], __ATOMIC_ACQUIRE,
                             __HIP_MEMORY_SCOPE_AGENT) < nblk)
      __builtin_amdgcn_s_sleep(2);
  }
  __syncthreads();

  // ---- row phase: wave w handles row i = 4r + w ----
  const int i = 4 * r + w;
  const float* pb = partials + (size_t)i * B_DIM + 4 * lane;
  float4 s4 = make_float4(0.f, 0.f, 0.f, 0.f);
#pragma unroll 8
  for (int c = 0; c < C; ++c) {
    const float4 v = *(const float4*)(pb + (size_t)c * (B_DIM * B_DIM));
    s4.x += v.x;
    s4.y += v.y;
    s4.z += v.z;
    s4.w += v.w;
  }
  const float lg0 = s4.x * TEMP, lg1 = s4.y * TEMP;
  const float lg2 = s4.z * TEMP, lg3 = s4.w * TEMP;
  *(float4*)&logits[(size_t)i * B_DIM + 4 * lane] =
      make_float4(lg0, lg1, lg2, lg3);
  // |lg| <= 14.3 by Cauchy-Schwarz: no max-shift needed
  float e = expf(lg0) + expf(lg1) + expf(lg2) + expf(lg3);
#pragma unroll
  for (int off = 32; off > 0; off >>= 1) e += __shfl_xor(e, off);
  // positive logit: row i, col i -> lane i>>2, component i&3 (static select)
  const int pc = i & 3;
  const float lsel = (pc == 0) ? lg0 : (pc == 1) ? lg1 : (pc == 2) ? lg2 : lg3;
  const float pv = __shfl(lsel, i >> 2, 64);
  __shared__ float warr[4];
  if (lane == 0) warr[w] = logf(e) - 2.f * pv;

  // ---- barrier among the 64 finalizers (logits must be visible) ----
  __syncthreads();  // drains logits stores
  if (t == 0) {
    __hip_atomic_fetch_add(&ctr[1], 1u, __ATOMIC_ACQ_REL,
                           __HIP_MEMORY_SCOPE_AGENT);
    while (__hip_atomic_load(&ctr[1], __ATOMIC_ACQUIRE,
                             __HIP_MEMORY_SCOPE_AGENT) < NFIN)
      __builtin_amdgcn_s_sleep(2);
  }
  __syncthreads();

  // ---- col phase: wave w handles col j = 4r + w ----
  const int j = 4 * r + w;
  float ce = 0.f;
#pragma unroll
  for (int k = 0; k < 4; ++k)
    ce += expf(logits[(size_t)(4 * lane + k) * B_DIM + j]);
#pragma unroll
  for (int off = 32; off > 0; off >>= 1) ce += __shfl_xor(ce, off);
  if (lane == 0) warr[w] += logf(ce);
  __syncthreads();

  // ---- final: 64 block-sums -> device-coherent float atomic -> out ----
  if (t == 0) {
    const float bs = warr[0] + warr[1] + warr[2] + warr[3];
    atomicAdd((float*)(ctr + 3), bs);  // device-scope, coherent
    const unsigned o3 = __hip_atomic_fetch_add(&ctr[2], 1u, __ATOMIC_ACQ_REL,
                                               __HIP_MEMORY_SCOPE_AGENT);
    if (o3 == NFIN - 1) {
      // every block's accf-add precedes its ctr[2] release; acquire saw all 64
      const float tot = __hip_atomic_load((float*)(ctr + 3), __ATOMIC_ACQUIRE,
                                          __HIP_MEMORY_SCOPE_AGENT);
      out[0] = tot * (0.5f / 256.f);
    }
  }
}

extern "C" void kernel_launch(void* const* d_in, const int* in_sizes, int n_in,
                              void* d_out, int out_size, void* d_ws, size_t ws_size,
                              hipStream_t stream) {
  (void)in_sizes; (void)n_in; (void)out_size;
  const float* A = (const float*)d_in[0];
  const float* Bm = (const float*)d_in[1];
  float* out = (float*)d_out;

  // ws layout: [logits 256*256 f32][partials C*256*256 f32][ctr: 3 u32 + accf]
  const size_t per = (size_t)B_DIM * B_DIM * sizeof(float);  // 256 KB
  int C = 128;
  while (C > 1 && (size_t)(C + 1) * per + 16 > ws_size) C >>= 1;
  const int Kc = D_DIM / C;

  float* logits = (float*)d_ws;
  float* partials = (float*)d_ws + (size_t)B_DIM * B_DIM;
  unsigned* ctr = (unsigned*)(partials + (size_t)C * B_DIM * B_DIM);

  hipMemsetAsync(ctr, 0, 16, stream);  // counters + float accumulator
  mega<<<4 * C, 256, 0, stream>>>(A, Bm, partials, logits, ctr, out, Kc, C);
}